// Round 7
// baseline (2351.314 us; speedup 1.0000x reference)
//
#include <hip/hip_runtime.h>
#include <math.h>
#include <stdint.h>

#define N_NODES 50000
#define N_EDGES 400000
#define N_T 4
#define N_R 8
#define N_H 8
#define DKD 32
#define D 256
#define TM 64
#define N_SEG (N_NODES * N_R)
#define PROJ_BLOCKS ((N_NODES + TM - 1) / TM + N_T)   // 786 >= sum of per-type ceils

typedef _Float16 h2 __attribute__((ext_vector_type(2)));
typedef _Float16 v8h __attribute__((ext_vector_type(8)));
typedef float v4f __attribute__((ext_vector_type(4)));
typedef unsigned short u16;

__device__ __forceinline__ u16 h2u(_Float16 h) { return __builtin_bit_cast(u16, h); }
__device__ __forceinline__ h2 u2h2(unsigned int u) { return __builtin_bit_cast(h2, u); }

// dot2 of f16 pairs with f32 accumulate: v_dot2_f32_f16 (1 instr = 2 MAC)
#if __has_builtin(__builtin_amdgcn_fdot2)
__device__ __forceinline__ float fdot2f(h2 a, h2 b, float c) {
    return __builtin_amdgcn_fdot2(a, b, c, false);
}
#else
__device__ __forceinline__ float fdot2f(h2 a, h2 b, float c) {
    return c + (float)a[0] * (float)b[0] + (float)a[1] * (float)b[1];
}
#endif

__device__ __forceinline__ unsigned int pk16(float a, float b) {
#if __has_builtin(__builtin_amdgcn_cvt_pkrtz)
    return __builtin_bit_cast(unsigned int, __builtin_amdgcn_cvt_pkrtz(a, b));
#else
    return __builtin_bit_cast(unsigned int, h2{(_Float16)a, (_Float16)b});
#endif
}

struct Q4 { uint4 a, b, c, d; };

// 32-elem f16 dot: 64B row (4 uint4) . register operand — 16 fdot2
__device__ __forceinline__ float dot32q(const uint4* __restrict__ m, const Q4& q) {
    uint4 m0 = m[0], m1 = m[1], m2 = m[2], m3 = m[3];
    float s = 0.f;
    s = fdot2f(u2h2(m0.x), u2h2(q.a.x), s);
    s = fdot2f(u2h2(m0.y), u2h2(q.a.y), s);
    s = fdot2f(u2h2(m0.z), u2h2(q.a.z), s);
    s = fdot2f(u2h2(m0.w), u2h2(q.a.w), s);
    s = fdot2f(u2h2(m1.x), u2h2(q.b.x), s);
    s = fdot2f(u2h2(m1.y), u2h2(q.b.y), s);
    s = fdot2f(u2h2(m1.z), u2h2(q.b.z), s);
    s = fdot2f(u2h2(m1.w), u2h2(q.b.w), s);
    s = fdot2f(u2h2(m2.x), u2h2(q.c.x), s);
    s = fdot2f(u2h2(m2.y), u2h2(q.c.y), s);
    s = fdot2f(u2h2(m2.z), u2h2(q.c.z), s);
    s = fdot2f(u2h2(m2.w), u2h2(q.c.w), s);
    s = fdot2f(u2h2(m3.x), u2h2(q.d.x), s);
    s = fdot2f(u2h2(m3.y), u2h2(q.d.y), s);
    s = fdot2f(u2h2(m3.z), u2h2(q.d.z), s);
    s = fdot2f(u2h2(m3.w), u2h2(q.d.w), s);
    return s;
}

// ---------------- f32 -> f16 weight conversions ----------------
__global__ __launch_bounds__(256) void k_cvtW(
    const float4* __restrict__ w0, const float4* __restrict__ w1,
    const float4* __restrict__ w2, const float4* __restrict__ w3,
    ushort4* __restrict__ d, int n4each) {
    int i = blockIdx.x * 256 + threadIdx.x;
    if (i >= 4 * n4each) return;
    int sel = i / n4each, j = i - sel * n4each;
    const float4* s = (sel == 0) ? w0 : (sel == 1) ? w1 : (sel == 2) ? w2 : w3;
    float4 v = s[j];
    ushort4 o;
    o.x = h2u((_Float16)v.x); o.y = h2u((_Float16)v.y);
    o.z = h2u((_Float16)v.z); o.w = h2u((_Float16)v.w);
    d[i] = o;
}

// rel_att scaled by pri[r][h]/sqrt(dk)*log2(e) folded in (softmax via exp2)
__global__ __launch_bounds__(256) void k_cvt_att(const float4* __restrict__ s,
                                                 const float* __restrict__ pri,
                                                 ushort4* __restrict__ d, int n4) {
    int i = blockIdx.x * 256 + threadIdx.x;
    if (i >= n4) return;
    int mat = i >> 8;                         // 1024 elems = 256 float4 per matrix
    float sc = pri[mat] * 0.2550309305920868f;   // (1/sqrt(32)) * log2(e)
    float4 v = s[i];
    ushort4 o;
    o.x = h2u((_Float16)(v.x * sc)); o.y = h2u((_Float16)(v.y * sc));
    o.z = h2u((_Float16)(v.z * sc)); o.w = h2u((_Float16)(v.w * sc));
    d[i] = o;
}

// rel_msg [mat][d0][f] f32 -> Mt [mat][f][d0] f16 (per 32x32 matrix transpose)
__global__ __launch_bounds__(256) void k_cvt_t(const float* __restrict__ s,
                                               u16* __restrict__ d) {
    int i = blockIdx.x * 256 + threadIdx.x;
    if (i >= N_R * N_H * DKD * DKD) return;
    int mat = i >> 10, w = i & 1023;
    int d0 = w >> 5, f = w & 31;
    d[(mat << 10) + f * DKD + d0] = h2u((_Float16)s[i]);
}

// ---------------- bucketing by node type ----------------
__global__ void k_hist(const int* __restrict__ nt, int* __restrict__ cnt) {
    int n = blockIdx.x * blockDim.x + threadIdx.x;
    if (n < N_NODES) atomicAdd(&cnt[nt[n]], 1);
}

__global__ void k_scan(const int* __restrict__ cnt, int* __restrict__ off,
                       int* __restrict__ toff) {
    int o = 0, to = 0;
    for (int t = 0; t < N_T; t++) {
        off[t] = o; toff[t] = to;
        o += cnt[t]; to += (cnt[t] + TM - 1) / TM;
    }
    off[N_T] = o; toff[N_T] = to;
}

__global__ void k_scatter(const int* __restrict__ nt, const int* __restrict__ off,
                          int* __restrict__ cur, int* __restrict__ order) {
    int n = blockIdx.x * blockDim.x + threadIdx.x;
    if (n >= N_NODES) return;
    int t = nt[n];
    int pos = off[t] + atomicAdd(&cur[t], 1);
    order[pos] = n;
}

// ---------------- segment CSR (seg = dst*R + etype) ----------------
__global__ void k_hist_seg(const int* __restrict__ dst, const int* __restrict__ et,
                           int* __restrict__ cnt) {
    int e = blockIdx.x * blockDim.x + threadIdx.x;
    if (e < N_EDGES) atomicAdd(&cnt[dst[e] * N_R + et[e]], 1);
}

// level 1: per-block (1024) exclusive scan + block sums
__global__ __launch_bounds__(1024) void k_scan_l1(const int* __restrict__ cnt,
                                                  int* __restrict__ excl,
                                                  int* __restrict__ bsum) {
    __shared__ int sh[1024];
    int tid = threadIdx.x, i = blockIdx.x * 1024 + tid;
    int v = (i < N_SEG) ? cnt[i] : 0;
    sh[tid] = v;
    __syncthreads();
    #pragma unroll
    for (int ofs = 1; ofs < 1024; ofs <<= 1) {
        int t = (tid >= ofs) ? sh[tid - ofs] : 0;
        __syncthreads();
        sh[tid] += t;
        __syncthreads();
    }
    if (i < N_SEG) excl[i] = sh[tid] - v;
    if (tid == 1023) bsum[blockIdx.x] = sh[1023];
}

// level 2: single block exclusive scan of block sums (NB <= 512)
__global__ __launch_bounds__(512) void k_scan_l2(int* __restrict__ bsum, int NB) {
    __shared__ int sh[512];
    int tid = threadIdx.x;
    int v = (tid < NB) ? bsum[tid] : 0;
    sh[tid] = v;
    __syncthreads();
    #pragma unroll
    for (int ofs = 1; ofs < 512; ofs <<= 1) {
        int t = (tid >= ofs) ? sh[tid - ofs] : 0;
        __syncthreads();
        sh[tid] += t;
        __syncthreads();
    }
    if (tid < NB) bsum[tid] = sh[tid] - v;
}

// level 3: add block offsets, set final rowptr entry
__global__ void k_scan_l3(int* __restrict__ excl, const int* __restrict__ bsum) {
    int i = blockIdx.x * blockDim.x + threadIdx.x;
    if (i < N_SEG) excl[i] += bsum[i >> 10];
    else if (i == N_SEG) excl[N_SEG] = N_EDGES;
}

// scatter src node id per segment slot
__global__ void k_scatter_seg(const int* __restrict__ src, const int* __restrict__ dst,
                              const int* __restrict__ et, const int* __restrict__ rp,
                              int* __restrict__ cur, int* __restrict__ esrc) {
    int e = blockIdx.x * blockDim.x + threadIdx.x;
    if (e >= N_EDGES) return;
    int sg = dst[e] * N_R + et[e];
    int pos = rp[sg] + atomicAdd(&cur[sg], 1);
    esrc[pos] = src[e];
}

// ---------------- fused typed K/Q/V projection (MFMA, f16) ----------------
// (Round-5 proven version: direct global stores.)
__global__ __launch_bounds__(256) void k_proj(
    const float* __restrict__ x, const int* __restrict__ order,
    const int* __restrict__ off, const int* __restrict__ toff,
    const u16* __restrict__ Wkb, const float* __restrict__ bk,
    const u16* __restrict__ Wqb, const float* __restrict__ bq,
    const u16* __restrict__ Wvb, const float* __restrict__ bv,
    u16* __restrict__ Kb, u16* __restrict__ Qb, u16* __restrict__ Vb) {
    __shared__ __align__(16) u16 xs[TM][D + 8];
    int b = blockIdx.x;
    int t = -1;
    #pragma unroll
    for (int i = 0; i < N_T; i++)
        if (b >= toff[i] && b < toff[i + 1]) t = i;
    if (t < 0) return;
    int nodeBase = off[t] + (b - toff[t]) * TM;
    int count = min(TM, off[t + 1] - nodeBase);
    int tid = threadIdx.x;

    for (int j = tid; j < TM * (D / 4); j += 256) {
        int row = j >> 6, ch = j & 63;
        float4 v = {0.f, 0.f, 0.f, 0.f};
        if (row < count) {
            int g = order[nodeBase + row];
            v = *(const float4*)(x + (size_t)g * D + ch * 4);
        }
        ushort4 o;
        o.x = h2u((_Float16)v.x); o.y = h2u((_Float16)v.y);
        o.z = h2u((_Float16)v.z); o.w = h2u((_Float16)v.w);
        *(ushort4*)&xs[row][ch * 4] = o;
    }
    __syncthreads();

    int lane = tid & 63, wave = tid >> 6;
    int m = lane & 15, quad = lane >> 4;
    v8h a[8];
    #pragma unroll
    for (int ks = 0; ks < 8; ks++)
        a[ks] = *(const v8h*)&xs[wave * 16 + m][ks * 32 + quad * 8];

    int grow[4]; bool vrow[4];
    #pragma unroll
    for (int r = 0; r < 4; r++) {
        int rowi = wave * 16 + quad * 4 + r;
        vrow[r] = (rowi < count);
        grow[r] = vrow[r] ? order[nodeBase + rowi] : 0;
    }

    const u16* Ws[3] = {Wkb + (size_t)t * D * D, Wqb + (size_t)t * D * D, Wvb + (size_t)t * D * D};
    const float* Bs[3] = {bk + t * D, bq + t * D, bv + t * D};
    u16* Os[3] = {Kb, Qb, Vb};

    for (int p = 0; p < 3; p++) {
        const u16* W = Ws[p];
        for (int dt = 0; dt < 16; dt++) {
            int dcol = dt * 16 + m;
            v4f acc = {0.f, 0.f, 0.f, 0.f};
            #pragma unroll
            for (int ks = 0; ks < 8; ks++) {
                v8h bf = *(const v8h*)(W + (size_t)dcol * D + ks * 32 + quad * 8);
                acc = __builtin_amdgcn_mfma_f32_16x16x32_f16(a[ks], bf, acc, 0, 0, 0);
            }
            float bias = Bs[p][dcol];
            #pragma unroll
            for (int r = 0; r < 4; r++) {
                if (vrow[r])
                    Os[p][(size_t)grow[r] * D + dcol] = h2u((_Float16)(acc[r] + bias));
            }
        }
    }
}

// ---------------- fused attention + softmax + aggregation + msg transform ----
// Wave per node; lane = j*8 + h (j = edge slot 0..7, h = head 0..7).
// HARDENED vs round 6: (1) segment bounds go through readfirstlane so all
// per-r branches are provably scalar-uniform (exec mask stays full for every
// __shfl); (2) qt cooperative compute + exchange is UNCONDITIONAL per r —
// cross-lane ops never sit inside a conditional region.
__global__ __launch_bounds__(256) void k_fused(
    const u16* __restrict__ Kb, u16* QTb, const u16* __restrict__ Vb,
    const int* __restrict__ rowptr, const int* __restrict__ esrc,
    const u16* __restrict__ Ab, const u16* __restrict__ Mtb) {
    int wave = threadIdx.x >> 6, lane = threadIdx.x & 63;
    int n = blockIdx.x * 4 + wave;
    if (n >= N_NODES) return;
    int j = lane >> 3, h = lane & 7;
    int base = n * N_R;

    int bnd[N_R + 1];
    #pragma unroll
    for (int i = 0; i <= N_R; i++)
        bnd[i] = __builtin_amdgcn_readfirstlane(rowptr[base + i]);

    // own head slice of Q (8 j-lanes of same h share the same 64B)
    Q4 q4;
    {
        const uint4* qp = (const uint4*)(QTb + (size_t)n * D + h * DKD);
        q4.a = qp[0]; q4.b = qp[1]; q4.c = qp[2]; q4.d = qp[3];
    }

    float macc[4] = {0.f, 0.f, 0.f, 0.f};
    float np = 0.f;

    for (int r = 0; r < N_R; r++) {
        int s0 = bnd[r], s1 = bnd[r + 1];

        // ---- cooperative qtilde (UNCONDITIONAL): lane computes rows 4j..4j+3 ----
        const uint4* Ar = (const uint4*)(Ab + ((size_t)(r * N_H + h) << 10));
        float t0 = dot32q(Ar + (4 * j + 0) * 4, q4);
        float t1 = dot32q(Ar + (4 * j + 1) * 4, q4);
        float t2 = dot32q(Ar + (4 * j + 2) * 4, q4);
        float t3 = dot32q(Ar + (4 * j + 3) * 4, q4);
        unsigned int qp0 = pk16(t0, t1), qp1 = pk16(t2, t3);
        // all-to-all across j (lane jj*8+h holds rows 4jj..4jj+3 of head h)
        Q4 qt;
        qt.a.x = __shfl(qp0, 0 * 8 + h); qt.a.y = __shfl(qp1, 0 * 8 + h);
        qt.a.z = __shfl(qp0, 1 * 8 + h); qt.a.w = __shfl(qp1, 1 * 8 + h);
        qt.b.x = __shfl(qp0, 2 * 8 + h); qt.b.y = __shfl(qp1, 2 * 8 + h);
        qt.b.z = __shfl(qp0, 3 * 8 + h); qt.b.w = __shfl(qp1, 3 * 8 + h);
        qt.c.x = __shfl(qp0, 4 * 8 + h); qt.c.y = __shfl(qp1, 4 * 8 + h);
        qt.c.z = __shfl(qp0, 5 * 8 + h); qt.c.w = __shfl(qp1, 5 * 8 + h);
        qt.d.x = __shfl(qp0, 6 * 8 + h); qt.d.y = __shfl(qp1, 6 * 8 + h);
        qt.d.z = __shfl(qp0, 7 * 8 + h); qt.d.w = __shfl(qp1, 7 * 8 + h);

        if (s0 >= s1) continue;     // scalar-uniform (bnd from readfirstlane)
        np += 1.f;

        // ---- edge loop: 8 edges per iteration (lane j owns edge b0+j) ----
        float den_p = 0.f;
        float U[DKD];
        #pragma unroll
        for (int i = 0; i < DKD; i++) U[i] = 0.f;
        for (int b0 = s0; b0 < s1; b0 += 8) {
            int e = b0 + j;
            bool act = (e < s1);
            int s = esrc[act ? e : s0];
            const uint4* kp = (const uint4*)(Kb + (size_t)s * D + h * DKD);
            const uint4* vp = (const uint4*)(Vb + (size_t)s * D + h * DKD);
            Q4 kv; kv.a = kp[0]; kv.b = kp[1]; kv.c = kp[2]; kv.d = kp[3];
            uint4 v0 = vp[0], v1 = vp[1], v2 = vp[2], v3 = vp[3];
            float p = 0.f;
            p = fdot2f(u2h2(kv.a.x), u2h2(qt.a.x), p);
            p = fdot2f(u2h2(kv.a.y), u2h2(qt.a.y), p);
            p = fdot2f(u2h2(kv.a.z), u2h2(qt.a.z), p);
            p = fdot2f(u2h2(kv.a.w), u2h2(qt.a.w), p);
            p = fdot2f(u2h2(kv.b.x), u2h2(qt.b.x), p);
            p = fdot2f(u2h2(kv.b.y), u2h2(qt.b.y), p);
            p = fdot2f(u2h2(kv.b.z), u2h2(qt.b.z), p);
            p = fdot2f(u2h2(kv.b.w), u2h2(qt.b.w), p);
            p = fdot2f(u2h2(kv.c.x), u2h2(qt.c.x), p);
            p = fdot2f(u2h2(kv.c.y), u2h2(qt.c.y), p);
            p = fdot2f(u2h2(kv.c.z), u2h2(qt.c.z), p);
            p = fdot2f(u2h2(kv.c.w), u2h2(qt.c.w), p);
            p = fdot2f(u2h2(kv.d.x), u2h2(qt.d.x), p);
            p = fdot2f(u2h2(kv.d.y), u2h2(qt.d.y), p);
            p = fdot2f(u2h2(kv.d.z), u2h2(qt.d.z), p);
            p = fdot2f(u2h2(kv.d.w), u2h2(qt.d.w), p);
            float ex = act ? exp2f(p) : 0.f;       // log2e folded into A
            den_p += ex;
#define UACC(VV, J0) { h2 _t = u2h2(VV); U[J0] += ex * (float)_t[0]; U[J0 + 1] += ex * (float)_t[1]; }
            UACC(v0.x, 0)  UACC(v0.y, 2)  UACC(v0.z, 4)  UACC(v0.w, 6)
            UACC(v1.x, 8)  UACC(v1.y, 10) UACC(v1.z, 12) UACC(v1.w, 14)
            UACC(v2.x, 16) UACC(v2.y, 18) UACC(v2.z, 20) UACC(v2.w, 22)
            UACC(v3.x, 24) UACC(v3.y, 26) UACC(v3.z, 28) UACC(v3.w, 30)
#undef UACC
        }

        // ---- butterfly reduce over j (strides 8,16,32); all lanes get sums ----
        den_p += __shfl_xor(den_p, 8);
        den_p += __shfl_xor(den_p, 16);
        den_p += __shfl_xor(den_p, 32);
        #pragma unroll
        for (int i = 0; i < DKD; i++) {
            U[i] += __shfl_xor(U[i], 8);
            U[i] += __shfl_xor(U[i], 16);
            U[i] += __shfl_xor(U[i], 32);
        }
        float invd = 1.f / den_p;
        Q4 uh;
        uh.a.x = pk16(U[0] * invd, U[1] * invd);
        uh.a.y = pk16(U[2] * invd, U[3] * invd);
        uh.a.z = pk16(U[4] * invd, U[5] * invd);
        uh.a.w = pk16(U[6] * invd, U[7] * invd);
        uh.b.x = pk16(U[8] * invd, U[9] * invd);
        uh.b.y = pk16(U[10] * invd, U[11] * invd);
        uh.b.z = pk16(U[12] * invd, U[13] * invd);
        uh.b.w = pk16(U[14] * invd, U[15] * invd);
        uh.c.x = pk16(U[16] * invd, U[17] * invd);
        uh.c.y = pk16(U[18] * invd, U[19] * invd);
        uh.c.z = pk16(U[20] * invd, U[21] * invd);
        uh.c.w = pk16(U[22] * invd, U[23] * invd);
        uh.d.x = pk16(U[24] * invd, U[25] * invd);
        uh.d.y = pk16(U[26] * invd, U[27] * invd);
        uh.d.z = pk16(U[28] * invd, U[29] * invd);
        uh.d.w = pk16(U[30] * invd, U[31] * invd);

        // ---- M-transform: lane computes features 4j..4j+3 of head h ----
        const uint4* Mr = (const uint4*)(Mtb + ((size_t)(r * N_H + h) << 10));
        macc[0] += dot32q(Mr + (4 * j + 0) * 4, uh);
        macc[1] += dot32q(Mr + (4 * j + 1) * 4, uh);
        macc[2] += dot32q(Mr + (4 * j + 2) * 4, uh);
        macc[3] += dot32q(Mr + (4 * j + 3) * 4, uh);
    }

    float invp = (np > 0.f) ? 1.f / np : 1.f;
    unsigned int w0 = pk16(macc[0] * invp, macc[1] * invp);
    unsigned int w1 = pk16(macc[2] * invp, macc[3] * invp);
    uint2 ow = {w0, w1};
    *(uint2*)(QTb + (size_t)n * D + h * DKD + 4 * j) = ow;
}

// ---------------- typed output linear + sigmoid-skip blend (MFMA, f16) ----------------
// (Round-5 proven version: direct out/x element ops.)
__global__ __launch_bounds__(256) void k_out(
    const u16* __restrict__ TBF, const float* __restrict__ x,
    const int* __restrict__ order, const int* __restrict__ off, const int* __restrict__ toff,
    const u16* __restrict__ Wab, const float* __restrict__ ba,
    const float* __restrict__ skip, float* __restrict__ out) {
    __shared__ __align__(16) u16 xs[TM][D + 8];
    int b = blockIdx.x;
    int t = -1;
    #pragma unroll
    for (int i = 0; i < N_T; i++)
        if (b >= toff[i] && b < toff[i + 1]) t = i;
    if (t < 0) return;
    int nodeBase = off[t] + (b - toff[t]) * TM;
    int count = min(TM, off[t + 1] - nodeBase);
    int tid = threadIdx.x;

    for (int j = tid; j < TM * 32; j += 256) {
        int row = j >> 5, ch = j & 31;
        ushort4 z = {0, 0, 0, 0};
        if (row < count) {
            int g = order[nodeBase + row];
            const ushort4* p = (const ushort4*)(TBF + (size_t)g * D + ch * 8);
            *(ushort4*)&xs[row][ch * 8] = p[0];
            *(ushort4*)&xs[row][ch * 8 + 4] = p[1];
        } else {
            *(ushort4*)&xs[row][ch * 8] = z;
            *(ushort4*)&xs[row][ch * 8 + 4] = z;
        }
    }
    __syncthreads();

    int lane = tid & 63, wave = tid >> 6;
    int m = lane & 15, quad = lane >> 4;
    v8h a[8];
    #pragma unroll
    for (int ks = 0; ks < 8; ks++)
        a[ks] = *(const v8h*)&xs[wave * 16 + m][ks * 32 + quad * 8];

    int grow[4]; bool vrow[4];
    #pragma unroll
    for (int r = 0; r < 4; r++) {
        int rowi = wave * 16 + quad * 4 + r;
        vrow[r] = (rowi < count);
        grow[r] = vrow[r] ? order[nodeBase + rowi] : 0;
    }

    float sv = skip[t];
    float alpha = 1.f / (1.f + __expf(-sv));
    float beta = 1.f - alpha;
    const u16* W = Wab + (size_t)t * D * D;

    for (int dt = 0; dt < 16; dt++) {
        int dcol = dt * 16 + m;
        v4f acc = {0.f, 0.f, 0.f, 0.f};
        #pragma unroll
        for (int ks = 0; ks < 8; ks++) {
            v8h bf = *(const v8h*)(W + (size_t)dcol * D + ks * 32 + quad * 8);
            acc = __builtin_amdgcn_mfma_f32_16x16x32_f16(a[ks], bf, acc, 0, 0, 0);
        }
        float bias = ba[t * D + dcol];
        #pragma unroll
        for (int r = 0; r < 4; r++) {
            if (vrow[r]) {
                size_t o = (size_t)grow[r] * D + dcol;
                out[o] = alpha * (acc[r] + bias) + beta * x[o];
            }
        }
    }
}

// ---------------- launch ----------------
extern "C" void kernel_launch(void* const* d_in, const int* in_sizes, int n_in,
                              void* d_out, int out_size, void* d_ws, size_t ws_size,
                              hipStream_t stream) {
    const float* x       = (const float*)d_in[0];
    const int* node_type = (const int*)d_in[1];
    const int* src       = (const int*)d_in[2];
    const int* dst       = (const int*)d_in[3];
    const int* etype     = (const int*)d_in[4];
    const float* Wk = (const float*)d_in[5];
    const float* bk = (const float*)d_in[6];
    const float* Wq = (const float*)d_in[7];
    const float* bq = (const float*)d_in[8];
    const float* Wv = (const float*)d_in[9];
    const float* bv = (const float*)d_in[10];
    const float* Wa = (const float*)d_in[11];
    const float* ba = (const float*)d_in[12];
    const float* rel_pri = (const float*)d_in[13];
    const float* rel_att = (const float*)d_in[14];
    const float* rel_msg = (const float*)d_in[15];
    const float* skip    = (const float*)d_in[16];
    float* out = (float*)d_out;
    char* ws = (char*)d_ws;

    // ws (~79.7 MB): Kb | Qb | Vb (f16 node tensors), f16 weights, order,
    // counters. TBF aliases Qb (per-slice read-then-write by same wave).
    const size_t SZH = (size_t)N_NODES * D * 2;          // 25.6 MB
    const size_t WSZ = (size_t)N_T * D * D;              // 262144 elems
    const size_t RSZ = (size_t)N_R * N_H * DKD * DKD;    // 65536 elems
    u16* Kb  = (u16*)(ws);
    u16* Qb  = (u16*)(ws + SZH);
    u16* Vb  = (u16*)(ws + 2 * SZH);
    u16* TBF = Qb;                              // aliases Qb
    u16* Wkb = (u16*)(ws + 3 * SZH);
    u16* Wqb = Wkb + WSZ;
    u16* Wvb = Wqb + WSZ;
    u16* Wab = Wvb + WSZ;
    u16* Ab  = Wab + WSZ;
    u16* Mtb = Ab + RSZ;
    int* order = (int*)(Mtb + RSZ);
    int* small = order + N_NODES;
    int* cnt  = small;        // 4
    int* cur  = small + 4;    // 4
    int* offp = small + 8;    // 5
    int* toffp= small + 13;   // 5

    // d_out as scratch (all dead before k_out rewrites it):
    //   rowptr_seg[S+1] | cnt_seg[S] | cur_seg[S] | esrc[E] | bsum — ~6.4 MB of 51.2 MB
    char* ob = (char*)d_out;
    int* rowptr_seg = (int*)ob;                          // 400001
    int* cnt_seg    = rowptr_seg + (N_SEG + 16);         // 400000
    int* cur_seg    = cnt_seg + N_SEG;                   // 400000 (contiguous w/ cnt)
    int* esrc       = cur_seg + N_SEG;                   // 400000
    int* bsum       = esrc + N_EDGES;                    // 391 (+pad)

    hipMemsetAsync(small, 0, 8 * sizeof(int), stream);
    hipMemsetAsync(cnt_seg, 0, 2 * (size_t)N_SEG * sizeof(int), stream);

    // weight conversions (f32 -> f16)
    k_cvtW<<<(4 * (WSZ / 4) + 255) / 256, 256, 0, stream>>>(
        (const float4*)Wk, (const float4*)Wq, (const float4*)Wv, (const float4*)Wa,
        (ushort4*)Wkb, WSZ / 4);
    k_cvt_att<<<(RSZ / 4 + 255) / 256, 256, 0, stream>>>(
        (const float4*)rel_att, rel_pri, (ushort4*)Ab, RSZ / 4);
    k_cvt_t<<<(RSZ + 255) / 256, 256, 0, stream>>>(rel_msg, Mtb);

    // node-type buckets
    k_hist<<<(N_NODES + 255) / 256, 256, 0, stream>>>(node_type, cnt);
    k_scan<<<1, 1, 0, stream>>>(cnt, offp, toffp);
    k_scatter<<<(N_NODES + 255) / 256, 256, 0, stream>>>(node_type, offp, cur, order);

    // segment CSR (dst*R + etype)
    const int NB = (N_SEG + 1023) / 1024;                // 391
    k_hist_seg<<<(N_EDGES + 255) / 256, 256, 0, stream>>>(dst, etype, cnt_seg);
    k_scan_l1<<<NB, 1024, 0, stream>>>(cnt_seg, rowptr_seg, bsum);
    k_scan_l2<<<1, 512, 0, stream>>>(bsum, NB);
    k_scan_l3<<<(N_SEG + 1 + 255) / 256, 256, 0, stream>>>(rowptr_seg, bsum);
    k_scatter_seg<<<(N_EDGES + 255) / 256, 256, 0, stream>>>(src, dst, etype,
                                                             rowptr_seg, cur_seg, esrc);

    k_proj<<<PROJ_BLOCKS, 256, 0, stream>>>(x, order, offp, toffp,
                                            Wkb, bk, Wqb, bq, Wvb, bv, Kb, Qb, Vb);

    k_fused<<<(N_NODES + 3) / 4, 256, 0, stream>>>(Kb, Qb, Vb, rowptr_seg, esrc,
                                                   Ab, Mtb);

    k_out<<<PROJ_BLOCKS, 256, 0, stream>>>(TBF, x, order, offp, toffp,
                                           Wab, ba, skip, out);
}

// Round 8
// 2009.526 us; speedup vs baseline: 1.1701x; 1.1701x over previous
//
#include <hip/hip_runtime.h>
#include <math.h>
#include <stdint.h>

#define N_NODES 50000
#define N_EDGES 400000
#define N_T 4
#define N_R 8
#define N_H 8
#define DKD 32
#define D 256
#define TM 64
#define PROJ_BLOCKS ((N_NODES + TM - 1) / TM + N_T)   // 786 >= sum of per-type ceils

typedef _Float16 h2 __attribute__((ext_vector_type(2)));
typedef _Float16 v8h __attribute__((ext_vector_type(8)));
typedef float v4f __attribute__((ext_vector_type(4)));
typedef unsigned short u16;
typedef unsigned char u8;

__device__ __forceinline__ u16 h2u(_Float16 h) { return __builtin_bit_cast(u16, h); }
__device__ __forceinline__ h2 u2h2(unsigned int u) { return __builtin_bit_cast(h2, u); }

// dot2 of f16 pairs with f32 accumulate: v_dot2_f32_f16 (1 instr = 2 MAC)
#if __has_builtin(__builtin_amdgcn_fdot2)
__device__ __forceinline__ float fdot2f(h2 a, h2 b, float c) {
    return __builtin_amdgcn_fdot2(a, b, c, false);
}
#else
__device__ __forceinline__ float fdot2f(h2 a, h2 b, float c) {
    return c + (float)a[0] * (float)b[0] + (float)a[1] * (float)b[1];
}
#endif

__device__ __forceinline__ unsigned int pk16(float a, float b) {
#if __has_builtin(__builtin_amdgcn_cvt_pkrtz)
    return __builtin_bit_cast(unsigned int, __builtin_amdgcn_cvt_pkrtz(a, b));
#else
    return __builtin_bit_cast(unsigned int, h2{(_Float16)a, (_Float16)b});
#endif
}

// 32-element f16 dot (rows as 4x uint4 = 64B): 16 fdot2
__device__ __forceinline__ float dot32h(const uint4* __restrict__ a,
                                        const uint4* __restrict__ q) {
    float s = 0.f;
    #pragma unroll
    for (int j = 0; j < 4; j++) {
        uint4 av = a[j], qv = q[j];
        s = fdot2f(u2h2(av.x), u2h2(qv.x), s);
        s = fdot2f(u2h2(av.y), u2h2(qv.y), s);
        s = fdot2f(u2h2(av.z), u2h2(qv.z), s);
        s = fdot2f(u2h2(av.w), u2h2(qv.w), s);
    }
    return s;
}

// ---------------- f32 -> f16 weight conversions ----------------
__global__ __launch_bounds__(256) void k_cvtW(
    const float4* __restrict__ w0, const float4* __restrict__ w1,
    const float4* __restrict__ w2, const float4* __restrict__ w3,
    ushort4* __restrict__ d, int n4each) {
    int i = blockIdx.x * 256 + threadIdx.x;
    if (i >= 4 * n4each) return;
    int sel = i / n4each, j = i - sel * n4each;
    const float4* s = (sel == 0) ? w0 : (sel == 1) ? w1 : (sel == 2) ? w2 : w3;
    float4 v = s[j];
    ushort4 o;
    o.x = h2u((_Float16)v.x); o.y = h2u((_Float16)v.y);
    o.z = h2u((_Float16)v.z); o.w = h2u((_Float16)v.w);
    d[i] = o;
}

// rel_att scaled by pri[r][h]/sqrt(dk)*log2(e) folded in (softmax via exp2)
__global__ __launch_bounds__(256) void k_cvt_att(const float4* __restrict__ s,
                                                 const float* __restrict__ pri,
                                                 ushort4* __restrict__ d, int n4) {
    int i = blockIdx.x * 256 + threadIdx.x;
    if (i >= n4) return;
    int mat = i >> 8;                         // 1024 elems = 256 float4 per matrix
    float sc = pri[mat] * 0.2550309305920868f;   // (1/sqrt(32)) * log2(e)
    float4 v = s[i];
    ushort4 o;
    o.x = h2u((_Float16)(v.x * sc)); o.y = h2u((_Float16)(v.y * sc));
    o.z = h2u((_Float16)(v.z * sc)); o.w = h2u((_Float16)(v.w * sc));
    d[i] = o;
}

// rel_msg [mat][d0][f] f32 -> Mt [mat][f][d0] f16 (per 32x32 matrix transpose)
__global__ __launch_bounds__(256) void k_cvt_t(const float* __restrict__ s,
                                               u16* __restrict__ d) {
    int i = blockIdx.x * 256 + threadIdx.x;
    if (i >= N_R * N_H * DKD * DKD) return;
    int mat = i >> 10, w = i & 1023;
    int d0 = w >> 5, f = w & 31;
    d[(mat << 10) + f * DKD + d0] = h2u((_Float16)s[i]);
}

// ---------------- bucketing by node type ----------------
__global__ void k_hist(const int* __restrict__ nt, int* __restrict__ cnt) {
    int n = blockIdx.x * blockDim.x + threadIdx.x;
    if (n < N_NODES) atomicAdd(&cnt[nt[n]], 1);
}

__global__ void k_scan(const int* __restrict__ cnt, int* __restrict__ off,
                       int* __restrict__ toff) {
    int o = 0, to = 0;
    for (int t = 0; t < N_T; t++) {
        off[t] = o; toff[t] = to;
        o += cnt[t]; to += (cnt[t] + TM - 1) / TM;
    }
    off[N_T] = o; toff[N_T] = to;
}

__global__ void k_scatter(const int* __restrict__ nt, const int* __restrict__ off,
                          int* __restrict__ cur, int* __restrict__ order) {
    int n = blockIdx.x * blockDim.x + threadIdx.x;
    if (n >= N_NODES) return;
    int t = nt[n];
    int pos = off[t] + atomicAdd(&cur[t], 1);
    order[pos] = n;
}

// ---------------- node-level CSR (grouped by dst only) ----------------
// per-edge histogram + per-node etype-presence bitmask
__global__ void k_hist2(const int* __restrict__ dst, const int* __restrict__ et,
                        int* __restrict__ cnt2, int* __restrict__ presw) {
    int e = blockIdx.x * blockDim.x + threadIdx.x;
    if (e >= N_EDGES) return;
    int d = dst[e];
    atomicAdd(&cnt2[d], 1);
    atomicOr(&presw[d], 1 << et[e]);
}

// level 1: per-block (1024) exclusive scan of node counts -> nbase (ws) + bsum
__global__ __launch_bounds__(1024) void k_scan_l1(const int* __restrict__ cnt2,
                                                  int* __restrict__ nbase,
                                                  int* __restrict__ bsum) {
    __shared__ int sh[1024];
    int tid = threadIdx.x, i = blockIdx.x * 1024 + tid;
    int v = (i < N_NODES) ? cnt2[i] : 0;
    sh[tid] = v;
    __syncthreads();
    #pragma unroll
    for (int ofs = 1; ofs < 1024; ofs <<= 1) {
        int t = (tid >= ofs) ? sh[tid - ofs] : 0;
        __syncthreads();
        sh[tid] += t;
        __syncthreads();
    }
    if (i < N_NODES) nbase[i] = sh[tid] - v;
    if (tid == 1023) bsum[blockIdx.x] = sh[1023];
}

// level 2: single block exclusive scan of block sums (NB <= 512)
__global__ __launch_bounds__(512) void k_scan_l2(int* __restrict__ bsum, int NB) {
    __shared__ int sh[512];
    int tid = threadIdx.x;
    int v = (tid < NB) ? bsum[tid] : 0;
    sh[tid] = v;
    __syncthreads();
    #pragma unroll
    for (int ofs = 1; ofs < 512; ofs <<= 1) {
        int t = (tid >= ofs) ? sh[tid - ofs] : 0;
        __syncthreads();
        sh[tid] += t;
        __syncthreads();
    }
    if (tid < NB) bsum[tid] = sh[tid] - v;
}

// level 3: add block offsets, fold presence mask into bits 24..31
__global__ void k_scan_l3(int* __restrict__ nbase, const int* __restrict__ bsum,
                          const int* __restrict__ presw) {
    int i = blockIdx.x * blockDim.x + threadIdx.x;
    if (i < N_NODES)
        nbase[i] = (nbase[i] + bsum[i >> 10]) | (presw[i] << 24);   // base < 2^24
    else if (i == N_NODES)
        nbase[N_NODES] = N_EDGES;
}

// scatter per-edge src (u16) + etype (u8) into node-grouped stream in ws
__global__ void k_scatter2(const int* __restrict__ src, const int* __restrict__ dst,
                           const int* __restrict__ et, const int* __restrict__ nbase,
                           int* __restrict__ cur2,
                           u16* __restrict__ esrc16, u8* __restrict__ er8) {
    int e = blockIdx.x * blockDim.x + threadIdx.x;
    if (e >= N_EDGES) return;
    int d = dst[e];
    int pos = (nbase[d] & 0xFFFFFF) + atomicAdd(&cur2[d], 1);
    esrc16[pos] = (u16)src[e];
    er8[pos] = (u8)et[e];
}

// ---------------- fused typed K/Q/V projection (MFMA, f16) ----------------
__global__ __launch_bounds__(256) void k_proj(
    const float* __restrict__ x, const int* __restrict__ order,
    const int* __restrict__ off, const int* __restrict__ toff,
    const u16* __restrict__ Wkb, const float* __restrict__ bk,
    const u16* __restrict__ Wqb, const float* __restrict__ bq,
    const u16* __restrict__ Wvb, const float* __restrict__ bv,
    u16* __restrict__ Kb, u16* __restrict__ Qb, u16* __restrict__ Vb) {
    __shared__ __align__(16) u16 xs[TM][D + 8];
    int b = blockIdx.x;
    int t = -1;
    #pragma unroll
    for (int i = 0; i < N_T; i++)
        if (b >= toff[i] && b < toff[i + 1]) t = i;
    if (t < 0) return;
    int nodeBase = off[t] + (b - toff[t]) * TM;
    int count = min(TM, off[t + 1] - nodeBase);
    int tid = threadIdx.x;

    for (int j = tid; j < TM * (D / 4); j += 256) {
        int row = j >> 6, ch = j & 63;
        float4 v = {0.f, 0.f, 0.f, 0.f};
        if (row < count) {
            int g = order[nodeBase + row];
            v = *(const float4*)(x + (size_t)g * D + ch * 4);
        }
        ushort4 o;
        o.x = h2u((_Float16)v.x); o.y = h2u((_Float16)v.y);
        o.z = h2u((_Float16)v.z); o.w = h2u((_Float16)v.w);
        *(ushort4*)&xs[row][ch * 4] = o;
    }
    __syncthreads();

    int lane = tid & 63, wave = tid >> 6;
    int m = lane & 15, quad = lane >> 4;
    v8h a[8];
    #pragma unroll
    for (int ks = 0; ks < 8; ks++)
        a[ks] = *(const v8h*)&xs[wave * 16 + m][ks * 32 + quad * 8];

    int grow[4]; bool vrow[4];
    #pragma unroll
    for (int r = 0; r < 4; r++) {
        int rowi = wave * 16 + quad * 4 + r;
        vrow[r] = (rowi < count);
        grow[r] = vrow[r] ? order[nodeBase + rowi] : 0;
    }

    const u16* Ws[3] = {Wkb + (size_t)t * D * D, Wqb + (size_t)t * D * D, Wvb + (size_t)t * D * D};
    const float* Bs[3] = {bk + t * D, bq + t * D, bv + t * D};
    u16* Os[3] = {Kb, Qb, Vb};

    for (int p = 0; p < 3; p++) {
        const u16* W = Ws[p];
        for (int dt = 0; dt < 16; dt++) {
            int dcol = dt * 16 + m;
            v4f acc = {0.f, 0.f, 0.f, 0.f};
            #pragma unroll
            for (int ks = 0; ks < 8; ks++) {
                v8h bf = *(const v8h*)(W + (size_t)dcol * D + ks * 32 + quad * 8);
                acc = __builtin_amdgcn_mfma_f32_16x16x32_f16(a[ks], bf, acc, 0, 0, 0);
            }
            float bias = Bs[p][dcol];
            #pragma unroll
            for (int r = 0; r < 4; r++) {
                if (vrow[r])
                    Os[p][(size_t)grow[r] * D + dcol] = h2u((_Float16)(acc[r] + bias));
            }
        }
    }
}

// ---------------- fused attention + softmax + aggregation + msg transform ----
// Wave per node; lane = h*8 + fl owns head h, feature slice [fl*4,fl*4+4).
// r4 structure (proven): mixed-r edge stream, 4 edges/iteration, den[8]/ua[8][4]
// register accumulators via scalar-uniform switch. ALL index structures
// (nbase, esrc16, er8) live in d_ws — k_fused never touches d_out.
__global__ __launch_bounds__(256) void k_fused(
    const u16* __restrict__ Kb, u16* QTb, const u16* __restrict__ Vb,
    const int* __restrict__ nbase, const u16* __restrict__ esrc16,
    const u8* __restrict__ er8,
    const u16* __restrict__ Ab, const u16* __restrict__ Mtb) {
    __shared__ __align__(16) unsigned int Uldu[4][N_H][20];   // f16-packed U
    int wave = threadIdx.x >> 6, lane = threadIdx.x & 63;
    int n = blockIdx.x * 4 + wave;
    if (n >= N_NODES) return;
    int h = lane >> 3, fl = lane & 7, fo = fl * 4;

    int w0v = nbase[n], w1v = nbase[n + 1];
    int s0 = __builtin_amdgcn_readfirstlane(w0v) & 0xFFFFFF;
    int s1 = __builtin_amdgcn_readfirstlane(w1v) & 0xFFFFFF;
    int pres = (__builtin_amdgcn_readfirstlane(w0v) >> 24) & 0xFF;

    uint4 qv4[4];
    {
        const uint4* qp = (const uint4*)(QTb + (size_t)n * D + h * DKD);
        #pragma unroll
        for (int j = 0; j < 4; j++) qv4[j] = qp[j];
    }

    // ---- phase A: qtilde for present r only (pri/sqrt(dk)/log2e folded in Ab) ----
    h2 qt2[N_R][2];
    for (int r = 0; r < N_R; r++) {
        if (!(pres & (1 << r))) continue;          // scalar-uniform branch
        const u16* Ar = Ab + ((size_t)(r * N_H + h) * DKD + fo) * DKD;
        float q0 = dot32h((const uint4*)(Ar), qv4);
        float q1 = dot32h((const uint4*)(Ar + DKD), qv4);
        float q2 = dot32h((const uint4*)(Ar + 2 * DKD), qv4);
        float q3 = dot32h((const uint4*)(Ar + 3 * DKD), qv4);
        qt2[r][0] = h2{(_Float16)q0, (_Float16)q1};
        qt2[r][1] = h2{(_Float16)q2, (_Float16)q3};
    }

    // ---- phase B: mixed-r edge stream, 4-wide batches ----
    float den[N_R] = {0.f, 0.f, 0.f, 0.f, 0.f, 0.f, 0.f, 0.f};
    float ua[N_R][4] = {};

#define DOTQ(P, RS, KU) { \
    h2 _ka = u2h2((KU).x), _kb = u2h2((KU).y); \
    switch (RS) { \
    case 0: P = fdot2f(_kb, qt2[0][1], fdot2f(_ka, qt2[0][0], 0.f)); break; \
    case 1: P = fdot2f(_kb, qt2[1][1], fdot2f(_ka, qt2[1][0], 0.f)); break; \
    case 2: P = fdot2f(_kb, qt2[2][1], fdot2f(_ka, qt2[2][0], 0.f)); break; \
    case 3: P = fdot2f(_kb, qt2[3][1], fdot2f(_ka, qt2[3][0], 0.f)); break; \
    case 4: P = fdot2f(_kb, qt2[4][1], fdot2f(_ka, qt2[4][0], 0.f)); break; \
    case 5: P = fdot2f(_kb, qt2[5][1], fdot2f(_ka, qt2[5][0], 0.f)); break; \
    case 6: P = fdot2f(_kb, qt2[6][1], fdot2f(_ka, qt2[6][0], 0.f)); break; \
    default: P = fdot2f(_kb, qt2[7][1], fdot2f(_ka, qt2[7][0], 0.f)); break; } }

#define ACCR(R, EX, V0, V1, V2, V3) \
    den[R] += EX; ua[R][0] += EX*V0; ua[R][1] += EX*V1; ua[R][2] += EX*V2; ua[R][3] += EX*V3;

#define ACCE(RS, EX, VU) { \
    h2 _va = u2h2((VU).x), _vb = u2h2((VU).y); \
    float _v0 = (float)_va[0], _v1 = (float)_va[1]; \
    float _v2 = (float)_vb[0], _v3 = (float)_vb[1]; \
    switch (RS) { \
    case 0: ACCR(0, EX, _v0, _v1, _v2, _v3) break; \
    case 1: ACCR(1, EX, _v0, _v1, _v2, _v3) break; \
    case 2: ACCR(2, EX, _v0, _v1, _v2, _v3) break; \
    case 3: ACCR(3, EX, _v0, _v1, _v2, _v3) break; \
    case 4: ACCR(4, EX, _v0, _v1, _v2, _v3) break; \
    case 5: ACCR(5, EX, _v0, _v1, _v2, _v3) break; \
    case 6: ACCR(6, EX, _v0, _v1, _v2, _v3) break; \
    default: ACCR(7, EX, _v0, _v1, _v2, _v3) break; } }

    size_t hoff = (size_t)(h * DKD + fo);
    for (int w0 = s0; w0 < s1; w0 += 64) {
        int wcnt = min(64, s1 - w0);
        int myek = 0;
        if (lane < wcnt)
            myek = (int)esrc16[w0 + lane] | ((int)er8[w0 + lane] << 20);
        for (int i0 = 0; i0 < wcnt; i0 += 4) {
            int mc = wcnt - i0;
            int pk0 = __shfl(myek, i0);
            int pk1 = __shfl(myek, i0 + (mc > 1 ? 1 : 0));
            int pk2 = __shfl(myek, i0 + (mc > 2 ? 2 : 0));
            int pk3 = __shfl(myek, i0 + (mc > 3 ? 3 : 0));
            int s0e = pk0 & 0xFFFFF, s1e = pk1 & 0xFFFFF;
            int s2e = pk2 & 0xFFFFF, s3e = pk3 & 0xFFFFF;
            int r0 = __builtin_amdgcn_readfirstlane(pk0) >> 20;
            int r1 = __builtin_amdgcn_readfirstlane(pk1) >> 20;
            int r2 = __builtin_amdgcn_readfirstlane(pk2) >> 20;
            int r3 = __builtin_amdgcn_readfirstlane(pk3) >> 20;
            // issue all 8 loads up front (independent)
            uint2 ku0 = *(const uint2*)(Kb + (size_t)s0e * D + hoff);
            uint2 ku1 = *(const uint2*)(Kb + (size_t)s1e * D + hoff);
            uint2 ku2 = *(const uint2*)(Kb + (size_t)s2e * D + hoff);
            uint2 ku3 = *(const uint2*)(Kb + (size_t)s3e * D + hoff);
            uint2 vu0 = *(const uint2*)(Vb + (size_t)s0e * D + hoff);
            uint2 vu1 = *(const uint2*)(Vb + (size_t)s1e * D + hoff);
            uint2 vu2 = *(const uint2*)(Vb + (size_t)s2e * D + hoff);
            uint2 vu3 = *(const uint2*)(Vb + (size_t)s3e * D + hoff);
            float p0, p1, p2, p3;
            DOTQ(p0, r0, ku0);
            DOTQ(p1, r1, ku1);
            DOTQ(p2, r2, ku2);
            DOTQ(p3, r3, ku3);
            p0 += __shfl_xor(p0, 1); p1 += __shfl_xor(p1, 1);
            p2 += __shfl_xor(p2, 1); p3 += __shfl_xor(p3, 1);
            p0 += __shfl_xor(p0, 2); p1 += __shfl_xor(p1, 2);
            p2 += __shfl_xor(p2, 2); p3 += __shfl_xor(p3, 2);
            p0 += __shfl_xor(p0, 4); p1 += __shfl_xor(p1, 4);
            p2 += __shfl_xor(p2, 4); p3 += __shfl_xor(p3, 4);
            float ex0 = exp2f(p0), ex1 = exp2f(p1);
            float ex2 = exp2f(p2), ex3 = exp2f(p3);
            ACCE(r0, ex0, vu0);
            if (mc > 1) { ACCE(r1, ex1, vu1); }
            if (mc > 2) { ACCE(r2, ex2, vu2); }
            if (mc > 3) { ACCE(r3, ex3, vu3); }
        }
    }

    // ---- phase C: normalize + per-r message transform (f16 LDS exchange) ----
    float macc[4] = {0.f, 0.f, 0.f, 0.f};
    #pragma unroll
    for (int r = 0; r < N_R; r++) {
        if (!(pres & (1 << r))) continue;          // scalar-uniform branch
        float invd = 1.f / den[r];
        unsigned int pw0 = pk16(ua[r][0] * invd, ua[r][1] * invd);
        unsigned int pw1 = pk16(ua[r][2] * invd, ua[r][3] * invd);
        __builtin_amdgcn_wave_barrier();
        *(uint2*)&Uldu[wave][h][fl * 2] = uint2{pw0, pw1};    // wave-private scratch
        __builtin_amdgcn_wave_barrier();
        uint4 Um[4];
        #pragma unroll
        for (int j = 0; j < 4; j++)
            Um[j] = *(const uint4*)&Uldu[wave][h][4 * j];
        const u16* mp = Mtb + ((size_t)(r * N_H + h) * DKD + fo) * DKD;
        #pragma unroll
        for (int j = 0; j < 4; j++)
            macc[j] += dot32h((const uint4*)(mp + j * DKD), Um);
        __builtin_amdgcn_wave_barrier();
    }

    int np = __popc(pres);
    float invp = (np > 0) ? 1.f / (float)np : 1.f;
    ushort4 o;
    o.x = h2u((_Float16)(macc[0] * invp)); o.y = h2u((_Float16)(macc[1] * invp));
    o.z = h2u((_Float16)(macc[2] * invp)); o.w = h2u((_Float16)(macc[3] * invp));
    *(ushort4*)(QTb + (size_t)n * D + hoff) = o;
}

// ---------------- typed output linear + sigmoid-skip blend (MFMA, f16) ----------------
__global__ __launch_bounds__(256) void k_out(
    const u16* __restrict__ TBF, const float* __restrict__ x,
    const int* __restrict__ order, const int* __restrict__ off, const int* __restrict__ toff,
    const u16* __restrict__ Wab, const float* __restrict__ ba,
    const float* __restrict__ skip, float* __restrict__ out) {
    __shared__ __align__(16) u16 xs[TM][D + 8];
    int b = blockIdx.x;
    int t = -1;
    #pragma unroll
    for (int i = 0; i < N_T; i++)
        if (b >= toff[i] && b < toff[i + 1]) t = i;
    if (t < 0) return;
    int nodeBase = off[t] + (b - toff[t]) * TM;
    int count = min(TM, off[t + 1] - nodeBase);
    int tid = threadIdx.x;

    for (int j = tid; j < TM * 32; j += 256) {
        int row = j >> 5, ch = j & 31;
        ushort4 z = {0, 0, 0, 0};
        if (row < count) {
            int g = order[nodeBase + row];
            const ushort4* p = (const ushort4*)(TBF + (size_t)g * D + ch * 8);
            *(ushort4*)&xs[row][ch * 8] = p[0];
            *(ushort4*)&xs[row][ch * 8 + 4] = p[1];
        } else {
            *(ushort4*)&xs[row][ch * 8] = z;
            *(ushort4*)&xs[row][ch * 8 + 4] = z;
        }
    }
    __syncthreads();

    int lane = tid & 63, wave = tid >> 6;
    int m = lane & 15, quad = lane >> 4;
    v8h a[8];
    #pragma unroll
    for (int ks = 0; ks < 8; ks++)
        a[ks] = *(const v8h*)&xs[wave * 16 + m][ks * 32 + quad * 8];

    int grow[4]; bool vrow[4];
    #pragma unroll
    for (int r = 0; r < 4; r++) {
        int rowi = wave * 16 + quad * 4 + r;
        vrow[r] = (rowi < count);
        grow[r] = vrow[r] ? order[nodeBase + rowi] : 0;
    }

    float sv = skip[t];
    float alpha = 1.f / (1.f + __expf(-sv));
    float beta = 1.f - alpha;
    const u16* W = Wab + (size_t)t * D * D;

    for (int dt = 0; dt < 16; dt++) {
        int dcol = dt * 16 + m;
        v4f acc = {0.f, 0.f, 0.f, 0.f};
        #pragma unroll
        for (int ks = 0; ks < 8; ks++) {
            v8h bf = *(const v8h*)(W + (size_t)dcol * D + ks * 32 + quad * 8);
            acc = __builtin_amdgcn_mfma_f32_16x16x32_f16(a[ks], bf, acc, 0, 0, 0);
        }
        float bias = ba[t * D + dcol];
        #pragma unroll
        for (int r = 0; r < 4; r++) {
            if (vrow[r]) {
                size_t o = (size_t)grow[r] * D + dcol;
                out[o] = alpha * (acc[r] + bias) + beta * x[o];
            }
        }
    }
}

// ---------------- launch ----------------
extern "C" void kernel_launch(void* const* d_in, const int* in_sizes, int n_in,
                              void* d_out, int out_size, void* d_ws, size_t ws_size,
                              hipStream_t stream) {
    const float* x       = (const float*)d_in[0];
    const int* node_type = (const int*)d_in[1];
    const int* src       = (const int*)d_in[2];
    const int* dst       = (const int*)d_in[3];
    const int* etype     = (const int*)d_in[4];
    const float* Wk = (const float*)d_in[5];
    const float* bk = (const float*)d_in[6];
    const float* Wq = (const float*)d_in[7];
    const float* bq = (const float*)d_in[8];
    const float* Wv = (const float*)d_in[9];
    const float* bv = (const float*)d_in[10];
    const float* Wa = (const float*)d_in[11];
    const float* ba = (const float*)d_in[12];
    const float* rel_pri = (const float*)d_in[13];
    const float* rel_att = (const float*)d_in[14];
    const float* rel_msg = (const float*)d_in[15];
    const float* skip    = (const float*)d_in[16];
    float* out = (float*)d_out;
    char* ws = (char*)d_ws;

    // ws (~79.7 MB): Kb | Qb | Vb (f16 node tensors), f16 weights, order, small.
    // After k_proj, the dead Wkb/Wqb/Wvb region (1.5 MB) is REUSED for the
    // edge stream (esrc16 800KB | er8 400KB | nbase 200KB = 1.4 MB) so that
    // k_fused reads NO data from d_out. TBF aliases Qb.
    const size_t SZH = (size_t)N_NODES * D * 2;          // 25.6 MB
    const size_t WSZ = (size_t)N_T * D * D;              // 262144 elems
    const size_t RSZ = (size_t)N_R * N_H * DKD * DKD;    // 65536 elems
    u16* Kb  = (u16*)(ws);
    u16* Qb  = (u16*)(ws + SZH);
    u16* Vb  = (u16*)(ws + 2 * SZH);
    u16* TBF = Qb;                              // aliases Qb
    u16* Wkb = (u16*)(ws + 3 * SZH);
    u16* Wqb = Wkb + WSZ;
    u16* Wvb = Wqb + WSZ;
    u16* Wab = Wvb + WSZ;
    u16* Ab  = Wab + WSZ;
    u16* Mtb = Ab + RSZ;
    int* order = (int*)(Mtb + RSZ);
    int* small = order + N_NODES;
    int* cnt  = small;        // 4
    int* cur  = small + 4;    // 4
    int* offp = small + 8;    // 5
    int* toffp= small + 13;   // 5

    // edge stream aliases Wkb..Wvb (written only after k_proj completes)
    u16* esrc16 = Wkb;                                   // 800000 B
    u8*  er8    = (u8*)(esrc16 + N_EDGES);               // 400000 B
    int* nbase  = (int*)(er8 + N_EDGES);                 // 200004 B (<= 1.5 MB total)

    // d_out as scratch: CSR build counters only (dead before k_out rewrites it)
    char* ob = (char*)d_out;
    int* cnt2  = (int*)ob;                               // 50000
    int* cur2  = cnt2 + N_NODES;                         // 50000
    int* presw = cur2 + N_NODES;                         // 50000
    int* bsum  = presw + N_NODES;                        // 49 (+pad)

    hipMemsetAsync(small, 0, 8 * sizeof(int), stream);
    hipMemsetAsync(cnt2, 0, 3 * (size_t)N_NODES * sizeof(int), stream);

    // weight conversions (f32 -> f16)
    k_cvtW<<<(4 * (WSZ / 4) + 255) / 256, 256, 0, stream>>>(
        (const float4*)Wk, (const float4*)Wq, (const float4*)Wv, (const float4*)Wa,
        (ushort4*)Wkb, WSZ / 4);
    k_cvt_att<<<(RSZ / 4 + 255) / 256, 256, 0, stream>>>(
        (const float4*)rel_att, rel_pri, (ushort4*)Ab, RSZ / 4);
    k_cvt_t<<<(RSZ + 255) / 256, 256, 0, stream>>>(rel_msg, Mtb);

    // node-type buckets
    k_hist<<<(N_NODES + 255) / 256, 256, 0, stream>>>(node_type, cnt);
    k_scan<<<1, 1, 0, stream>>>(cnt, offp, toffp);
    k_scatter<<<(N_NODES + 255) / 256, 256, 0, stream>>>(node_type, offp, cur, order);

    // projections FIRST (weights die here; their space becomes the edge stream)
    k_proj<<<PROJ_BLOCKS, 256, 0, stream>>>(x, order, offp, toffp,
                                            Wkb, bk, Wqb, bq, Wvb, bv, Kb, Qb, Vb);

    // node-level CSR build (scratch in d_out; results in ws)
    const int NB = (N_NODES + 1023) / 1024;              // 49
    k_hist2<<<(N_EDGES + 255) / 256, 256, 0, stream>>>(dst, etype, cnt2, presw);
    k_scan_l1<<<NB, 1024, 0, stream>>>(cnt2, nbase, bsum);
    k_scan_l2<<<1, 512, 0, stream>>>(bsum, NB);
    k_scan_l3<<<(N_NODES + 1 + 255) / 256, 256, 0, stream>>>(nbase, bsum, presw);
    k_scatter2<<<(N_EDGES + 255) / 256, 256, 0, stream>>>(src, dst, etype, nbase,
                                                          cur2, esrc16, er8);

    k_fused<<<(N_NODES + 3) / 4, 256, 0, stream>>>(Kb, Qb, Vb, nbase, esrc16, er8,
                                                   Ab, Mtb);

    k_out<<<PROJ_BLOCKS, 256, 0, stream>>>(TBF, x, order, offp, toffp,
                                           Wab, ba, skip, out);
}